// Round 5
// baseline (153.671 us; speedup 1.0000x reference)
//
#include <hip/hip_runtime.h>

#define B_    16
#define CIN_  128
#define COUT_ 256
#define H_    56
#define W_    56
#define YP    58
#define XP    64

typedef int   i32x4 __attribute__((ext_vector_type(4)));
typedef float f32x4 __attribute__((ext_vector_type(4)));

#define BH_SZ 16640        // per-buffer bytes: 4 rows x 64 x x 64 k + guard
#define EP_STRIDE 68       // fp32 elems per cout row in epilogue image (16B-mult)

// async global->LDS, 16B per lane; LDS dest wave-uniform base, lane l lands
// at base + l*16.
__device__ __forceinline__ void gload16(const void* g, void* l) {
    __builtin_amdgcn_global_load_lds(
        (const __attribute__((address_space(1))) unsigned int*)g,
        (__attribute__((address_space(3))) unsigned int*)l,
        16, 0, 0);
}

// ---------------------------------------------------------------------------
// Fused prep kernel, block-range partitioned:
//   [0,928)      : quantize x -> xqU i8 (u = xq/2-128, pad = -128) + s_pad
//   [928,1216)   : pack weights -> i8 tiles [tile(36)][m(128)][k(64)]
//   [1216,1232)  : Wsum[cout] = sum over cin,ky,kx of weight
__global__ __launch_bounds__(256) void k_prep(
    const float* __restrict__ x, const float* __restrict__ w,
    const float* __restrict__ p_act_s, const float* __restrict__ p_act_q,
    const float* __restrict__ p_azp,  const float* __restrict__ p_guard_a,
    signed char* __restrict__ xqU, signed char* __restrict__ wt,
    float* __restrict__ s_pad, float* __restrict__ Wsum)
{
    int t = threadIdx.x;
    int blk = blockIdx.x;

    if (blk < 928) {
        // ---- quantize one (b, padded-y) row ----
        int b = blk / YP, y = blk - b * YP;
        __shared__ signed char shq[W_ * 144];   // [w][cin], stride 144 (16-mult)
        signed char* orow = xqU + (size_t)blk * XP * CIN_;

        if (y == 0 || y == YP - 1) {
            i32x4 pv = {(int)0x80808080, (int)0x80808080,
                        (int)0x80808080, (int)0x80808080};
            *(i32x4*)(orow + t * 32)      = pv;
            *(i32x4*)(orow + t * 32 + 16) = pv;
            if (t < XP) s_pad[(size_t)blk * XP + t] = 0.0f;
            return;
        }
        int h = y - 1;
        float act_s = p_act_s[0], act_q = p_act_q[0];
        float azp = p_azp[0], ga = p_guard_a[0];
        float zp = azp * act_s / ga;
        float hi = zp + act_q - act_s;
        float inv_s = 1.0f / act_s;            // act_s = 2^-4: exact

        for (int i = 0; i < 28; ++i) {
            int e = i * 256 + t;               // < 7168
            int cin = e / 56;
            int ww = e - cin * 56;
            float v = x[(((size_t)b * CIN_ + cin) * H_ + h) * W_ + ww];
            v = fminf(fmaxf(v, zp), hi);
            float r = rintf((v - zp) * inv_s);        // [0,255] integer
            float uq = rintf(ga * r * 0.5f) - 128.0f; // = r-128 (ga==2)
            shq[ww * 144 + cin] = (signed char)(int)uq;
        }
        __syncthreads();
        // write padded row (16B stores, cin contiguous) + channel-sum
        #pragma unroll
        for (int i = 0; i < 2; ++i) {
            int T = i * 256 + t;               // < 512
            int xx = T >> 3;                   // 0..63
            int c16 = T & 7;
            union { i32x4 v; signed char c[16]; } u;
            if (xx >= 1 && xx <= W_) {
                u.v = *(const i32x4*)(shq + (xx - 1) * 144 + c16 * 16);
            } else {
                u.v = (i32x4){(int)0x80808080, (int)0x80808080,
                              (int)0x80808080, (int)0x80808080};
            }
            *(i32x4*)(orow + (size_t)xx * CIN_ + c16 * 16) = u.v;
            int sum = 0;
            #pragma unroll
            for (int j = 0; j < 16; ++j) sum += (int)u.c[j];
            sum += __shfl_xor(sum, 1);
            sum += __shfl_xor(sum, 2);
            sum += __shfl_xor(sum, 4);
            // sum(xq) = 2*sum(u) + 256*128; pads give exactly 0
            if (c16 == 0)
                s_pad[(size_t)blk * XP + xx] = (float)(2 * sum + 32768);
        }
        return;
    }

    if (blk < 1216) {
        // ---- weight pack: 4 consecutive k per thread ----
        int o = ((blk - 928) * 256 + t) * 4;   // < 294912
        int tile = o >> 13;                    // (g*2+cc)*2+cb
        int m    = (o >> 6) & 127;
        int kk   = o & 63;                     // multiple of 4
        int cb = tile & 1, cc = (tile >> 1) & 1, g = tile >> 2;
        int cout = cb * 128 + m;
        int cin0 = cc * 64 + kk;
        int dy = g / 3, dx = g - dy * 3;
        union { int v; signed char c[4]; } pk;
        #pragma unroll
        for (int j = 0; j < 4; ++j) {
            float v = w[(size_t)cout * 1152 + (cin0 + j) * 9 + dy * 3 + dx];
            pk.c[j] = (signed char)(int)v;
        }
        *(int*)(wt + o) = pk.v;
        return;
    }

    {
        // ---- Wsum: 16 couts per block, 16 lanes per cout ----
        int bw = blk - 1216;
        int cout = bw * 16 + (t >> 4);
        int part = t & 15;
        const float* base = w + (size_t)cout * 1152 + part * 72;
        float s = 0.f;
        for (int j = 0; j < 72; ++j) s += base[j];
        s += __shfl_xor(s, 1);
        s += __shfl_xor(s, 2);
        s += __shfl_xor(s, 4);
        s += __shfl_xor(s, 8);
        if (part == 0) Wsum[cout] = s;
        return;
    }
}

// ---------------------------------------------------------------------------
// i8 implicit-GEMM with barrier-light K-loop and LDS-transposed float4
// epilogue. Block tile 128(cout, via cb) x 128(n = 2 rows x 64 w).
//   A (weights) -> registers via global_load_dwordx4 (L2-hot, no LDS).
//   B (activation halo) staged to LDS once per cin-half, prefetched a full
//   cin-half early; 2 barriers in the K-loop.
//   Epilogue: acc -> LDS [cout][w] image -> w-contiguous float4
//   bias-load/FMA/store bursts (replaces 64 serialized scalar pairs).
__global__ __launch_bounds__(256, 3) void k_gemm(
    const signed char* __restrict__ xqU,  // [B][58][64][128] i8
    const signed char* __restrict__ wt,   // 36 tiles x [128][64] i8
    const float* __restrict__ s_pad,      // [B*58][64]
    const float* __restrict__ Wsum,       // [256]
    const float* __restrict__ wzp,        // [256]
    const float* __restrict__ fps,        // [256]
    const float* __restrict__ bias,       // [256][56][56]
    const float* __restrict__ p_gw,       // guard_w
    float* __restrict__ out)              // [B][256][56][56]
{
    __shared__ union {
        signed char bh[2][BH_SZ];                 // K-loop staging
        float       ep[128 * EP_STRIDE];          // epilogue transpose image
    } smem;
    __shared__ float c2s[2 * 56];

    int tid = threadIdx.x;
    int wv = tid >> 6, lane = tid & 63;
    int xl = lane & 15, q = lane >> 4;
    int p = blockIdx.x, cb = blockIdx.y;
    int b = p / 28, hp = p - b * 28;
    int h = hp * 2;                        // 2 output rows per block
    int wm0 = (wv >> 1) * 64;              // cout half within 128
    int row = wv & 1;                      // n half: output row 0/1

    // c2 box filter for this block's 2 output rows (s_pad L2-hot)
    if (tid < 112) {
        int rr = tid / 56, wp = tid - rr * 56;
        const float* sp = s_pad + ((size_t)(b * YP + h + rr)) * XP + wp;
        float a = 0.f;
        #pragma unroll
        for (int dy = 0; dy < 3; ++dy)
            #pragma unroll
            for (int dx = 0; dx < 3; ++dx)
                a += sp[dy * XP + dx];
        c2s[tid] = a;
    }

    const signed char* xb = xqU + (size_t)(b * YP + h) * XP * CIN_;

    // stage activation halo for cin-half cc_ into bh[buf_]; lane-permuted so
    // the LDS image carries the bank-swizzle (slot' = slot ^ ((x>>1)&3)).
    #define STAGE_B(buf_, cc_)                                              \
        {                                                                   \
            signed char* dstb = smem.bh[buf_];                              \
            _Pragma("unroll")                                               \
            for (int r_ = 0; r_ < 4; ++r_) {                                \
                int T_ = r_ * 256 + tid;                                    \
                int p_ = T_ & 3;                                            \
                int x_ = (T_ >> 2) & 63;                                    \
                int yy_ = T_ >> 8;                                          \
                int q_ = p_ ^ ((x_ >> 1) & 3);                              \
                gload16(xb + (size_t)(yy_ * XP + x_) * CIN_ + (cc_) * 64 + q_ * 16, \
                        dstb + (r_ * 256 + wv * 64) * 16);                  \
            }                                                               \
        }

    STAGE_B(0, 0)
    __syncthreads();      // bh[0] + c2s ready (vmcnt+lgkm drained)

    i32x4 acc[4][4];
    #pragma unroll
    for (int mi = 0; mi < 4; ++mi)
        #pragma unroll
        for (int ni = 0; ni < 4; ++ni)
            acc[mi][ni] = (i32x4){0, 0, 0, 0};

    int aoff = (wm0 + xl) * 64 + q * 16;   // bytes into a weight tile

    #pragma unroll
    for (int cc = 0; cc < 2; ++cc) {
        const signed char* Bb = smem.bh[cc];
        #pragma unroll
        for (int g = 0; g < 9; ++g) {
            if (cc == 0 && g == 0) STAGE_B(1, 1)   // prefetch far ahead
            int dy = g / 3, dx = g - dy * 3;
            const signed char* wtile =
                wt + (size_t)(((g * 2 + cc) * 2) + cb) * 8192;
            int slot = q ^ (((xl + dx) >> 1) & 3);
            int boff = (row + dy) * 4096 + (xl + dx) * 64 + slot * 16;
            i32x4 af[4], bf[4];
            #pragma unroll
            for (int mi = 0; mi < 4; ++mi)
                af[mi] = *(const i32x4*)(wtile + aoff + mi * 1024);
            #pragma unroll
            for (int ni = 0; ni < 4; ++ni)
                bf[ni] = *(const i32x4*)(Bb + boff + ni * 1024);
            #pragma unroll
            for (int mi = 0; mi < 4; ++mi)
                #pragma unroll
                for (int ni = 0; ni < 4; ++ni)
                    acc[mi][ni] = __builtin_amdgcn_mfma_i32_16x16x64_i8(
                        af[mi], bf[ni], acc[mi][ni], 0, 0, 0);
        }
        if (cc == 0) __syncthreads();   // bh[1] staging drained
    }

    __syncthreads();   // all LDS reads of bh done; smem is now ep

    // ---- epilogue: per output row, transpose acc through LDS, then
    //      w-contiguous float4 bias-load/FMA/store bursts ----
    float gw = p_gw[0];
    int cout_l = tid & 127;                    // this thread's cout (read phase)
    int half   = tid >> 7;                     // w half: 0 -> w<28, 1 -> w>=28
    int cout_g = cb * 128 + cout_l;
    float fs = fps[cout_g];
    float A  = gw * fs;                        // * ep (= 2*acc)
    float K0 = 256.0f * gw * Wsum[cout_g] * fs;
    float B0 = wzp[cout_g] * fs;

    #pragma unroll
    for (int r2 = 0; r2 < 2; ++r2) {
        // write phase: waves owning output-row r2 dump acc into ep image
        if (row == r2) {
            #pragma unroll
            for (int mi = 0; mi < 4; ++mi)
                #pragma unroll
                for (int ni = 0; ni < 4; ++ni)
                    #pragma unroll
                    for (int r = 0; r < 4; ++r)
                        smem.ep[(wm0 + mi * 16 + q * 4 + r) * EP_STRIDE +
                                ni * 16 + xl] = 2.0f * (float)acc[mi][ni][r];
        }
        __syncthreads();
        // read phase: all 256 threads; 7 float4 per thread along w
        {
            int hrow = h + r2;
            const float* brow = bias + ((size_t)cout_g * H_ + hrow) * W_;
            float* orow = out + (((size_t)b * COUT_ + cout_g) * H_ + hrow) * W_;
            const float* eprow = smem.ep + cout_l * EP_STRIDE;
            const float* c2row = c2s + r2 * 56;
            #pragma unroll
            for (int j = 0; j < 7; ++j) {
                int w4 = (half * 7 + j) * 4;   // 0..52, step 4
                f32x4 e = *(const f32x4*)(eprow + w4);
                f32x4 bi = *(const f32x4*)(brow + w4);
                f32x4 c2v = *(const f32x4*)(c2row + w4);
                f32x4 v;
                #pragma unroll
                for (int kq = 0; kq < 4; ++kq)
                    v[kq] = A * e[kq] + K0 + B0 * c2v[kq] + bi[kq];
                *(f32x4*)(orow + w4) = v;
            }
        }
        if (r2 == 0) __syncthreads();   // before row-1 waves overwrite ep
    }
}

// ---------------------------------------------------------------------------
extern "C" void kernel_launch(void* const* d_in, const int* in_sizes, int n_in,
                              void* d_out, int out_size, void* d_ws, size_t ws_size,
                              hipStream_t stream)
{
    const float* x     = (const float*)d_in[0];
    const float* wht   = (const float*)d_in[1];
    const float* act_s = (const float*)d_in[2];
    const float* act_q = (const float*)d_in[3];
    const float* azp   = (const float*)d_in[4];
    const float* wzp   = (const float*)d_in[5];
    const float* fps   = (const float*)d_in[6];
    const float* bias  = (const float*)d_in[7];
    const float* ga    = (const float*)d_in[8];
    const float* gw    = (const float*)d_in[9];
    float* out = (float*)d_out;

    char* ws = (char*)d_ws;
    // workspace (16B-aligned offsets):
    //   xqU  : 16*58*64*128 i8 = 7,602,176 B
    //   wt   : 294,912 B
    //   s_pad: 59,392 fp32     =   237,568 B
    //   Wsum : 256 fp32        =     1,024 B      (total ~8.1 MB)
    signed char* xqU  = (signed char*)(ws);
    signed char* wt   = (signed char*)(ws + 7602176);
    float*       spad = (float*)(ws + 7602176 + 294912);
    float*       Wsum = (float*)(ws + 7602176 + 294912 + 237568);

    k_prep<<<dim3(1232), dim3(256), 0, stream>>>(
        x, wht, act_s, act_q, azp, ga, xqU, wt, spad, Wsum);
    k_gemm<<<dim3(448, 2), dim3(256), 0, stream>>>(
        xqU, wt, spad, Wsum, wzp, fps, bias, gw, out);
}

// Round 6
// 150.211 us; speedup vs baseline: 1.0230x; 1.0230x over previous
//
#include <hip/hip_runtime.h>

#define B_    16
#define CIN_  128
#define COUT_ 256
#define H_    56
#define W_    56
#define YP    58
#define XP    64

typedef int   i32x4 __attribute__((ext_vector_type(4)));
typedef float f32x4 __attribute__((ext_vector_type(4)));

#define BH_SZ 16640        // per-buffer bytes: 4 rows x 64 x x 64 k + guard
#define EP_STRIDE 68       // fp32 elems per cout row in epilogue image

// async global->LDS, 16B per lane; LDS dest wave-uniform base, lane l lands
// at base + l*16.
__device__ __forceinline__ void gload16(const void* g, void* l) {
    __builtin_amdgcn_global_load_lds(
        (const __attribute__((address_space(1))) unsigned int*)g,
        (__attribute__((address_space(3))) unsigned int*)l,
        16, 0, 0);
}

// ---------------------------------------------------------------------------
// Fused prep kernel, block-range partitioned:
//   [0,928)      : quantize x -> xqU i8 (u = xq/2-128, pad = -128) + s_pad
//   [928,1216)   : pack weights -> i8 tiles [tile(36)][m(128)][k(64)]
//   [1216,1232)  : Wsum[cout] = sum over cin,ky,kx of weight
__global__ __launch_bounds__(256) void k_prep(
    const float* __restrict__ x, const float* __restrict__ w,
    const float* __restrict__ p_act_s, const float* __restrict__ p_act_q,
    const float* __restrict__ p_azp,  const float* __restrict__ p_guard_a,
    signed char* __restrict__ xqU, signed char* __restrict__ wt,
    float* __restrict__ s_pad, float* __restrict__ Wsum)
{
    int t = threadIdx.x;
    int blk = blockIdx.x;

    if (blk < 928) {
        // ---- quantize one (b, padded-y) row ----
        int b = blk / YP, y = blk - b * YP;
        __shared__ signed char shq[W_ * 144];   // [w][cin], stride 144 (16-mult)
        signed char* orow = xqU + (size_t)blk * XP * CIN_;

        if (y == 0 || y == YP - 1) {
            i32x4 pv = {(int)0x80808080, (int)0x80808080,
                        (int)0x80808080, (int)0x80808080};
            *(i32x4*)(orow + t * 32)      = pv;
            *(i32x4*)(orow + t * 32 + 16) = pv;
            if (t < XP) s_pad[(size_t)blk * XP + t] = 0.0f;
            return;
        }
        int h = y - 1;
        float act_s = p_act_s[0], act_q = p_act_q[0];
        float azp = p_azp[0], ga = p_guard_a[0];
        float zp = azp * act_s / ga;
        float hi = zp + act_q - act_s;
        float inv_s = 1.0f / act_s;            // act_s = 2^-4: exact

        for (int i = 0; i < 28; ++i) {
            int e = i * 256 + t;               // < 7168
            int cin = e / 56;
            int ww = e - cin * 56;
            float v = x[(((size_t)b * CIN_ + cin) * H_ + h) * W_ + ww];
            v = fminf(fmaxf(v, zp), hi);
            float r = rintf((v - zp) * inv_s);        // [0,255] integer
            float uq = rintf(ga * r * 0.5f) - 128.0f; // = r-128 (ga==2)
            shq[ww * 144 + cin] = (signed char)(int)uq;
        }
        __syncthreads();
        // write padded row (16B stores, cin contiguous) + channel-sum
        #pragma unroll
        for (int i = 0; i < 2; ++i) {
            int T = i * 256 + t;               // < 512
            int xx = T >> 3;                   // 0..63
            int c16 = T & 7;
            union { i32x4 v; signed char c[16]; } u;
            if (xx >= 1 && xx <= W_) {
                u.v = *(const i32x4*)(shq + (xx - 1) * 144 + c16 * 16);
            } else {
                u.v = (i32x4){(int)0x80808080, (int)0x80808080,
                              (int)0x80808080, (int)0x80808080};
            }
            *(i32x4*)(orow + (size_t)xx * CIN_ + c16 * 16) = u.v;
            int sum = 0;
            #pragma unroll
            for (int j = 0; j < 16; ++j) sum += (int)u.c[j];
            sum += __shfl_xor(sum, 1);
            sum += __shfl_xor(sum, 2);
            sum += __shfl_xor(sum, 4);
            // sum(xq) = 2*sum(u) + 256*128; pads give exactly 0
            if (c16 == 0)
                s_pad[(size_t)blk * XP + xx] = (float)(2 * sum + 32768);
        }
        return;
    }

    if (blk < 1216) {
        // ---- weight pack: 4 consecutive k per thread ----
        int o = ((blk - 928) * 256 + t) * 4;   // < 294912
        int tile = o >> 13;                    // (g*2+cc)*2+cb
        int m    = (o >> 6) & 127;
        int kk   = o & 63;                     // multiple of 4
        int cb = tile & 1, cc = (tile >> 1) & 1, g = tile >> 2;
        int cout = cb * 128 + m;
        int cin0 = cc * 64 + kk;
        int dy = g / 3, dx = g - dy * 3;
        union { int v; signed char c[4]; } pk;
        #pragma unroll
        for (int j = 0; j < 4; ++j) {
            float v = w[(size_t)cout * 1152 + (cin0 + j) * 9 + dy * 3 + dx];
            pk.c[j] = (signed char)(int)v;
        }
        *(int*)(wt + o) = pk.v;
        return;
    }

    {
        // ---- Wsum: 16 couts per block, 16 lanes per cout ----
        int bw = blk - 1216;
        int cout = bw * 16 + (t >> 4);
        int part = t & 15;
        const float* base = w + (size_t)cout * 1152 + part * 72;
        float s = 0.f;
        for (int j = 0; j < 72; ++j) s += base[j];
        s += __shfl_xor(s, 1);
        s += __shfl_xor(s, 2);
        s += __shfl_xor(s, 4);
        s += __shfl_xor(s, 8);
        if (part == 0) Wsum[cout] = s;
        return;
    }
}

// ---------------------------------------------------------------------------
// i8 implicit-GEMM, latency-pipelined K-loop:
//   - B (activation halo, BOTH cin-halves, 32 KB) staged to LDS once at block
//     start via global_load_lds; NO barrier inside the K-loop.
//   - K-loop g-outer (9 iters x 32 MFMA): A fragments for g+1 prefetched into
//     explicit registers before computing g -> 8 independent
//     global_load_dwordx4 in flight across each iteration's MFMA+ds_read work
//     (vmcnt(N!=0) pipelining). High VGPR budget is deliberate.
//   - Epilogue: acc -> LDS [cout][w] image -> w-contiguous float4 bursts.
__global__ __launch_bounds__(256, 2) void k_gemm(
    const signed char* __restrict__ xqU,  // [B][58][64][128] i8
    const signed char* __restrict__ wt,   // 36 tiles x [128][64] i8
    const float* __restrict__ s_pad,      // [B*58][64]
    const float* __restrict__ Wsum,       // [256]
    const float* __restrict__ wzp,        // [256]
    const float* __restrict__ fps,        // [256]
    const float* __restrict__ bias,       // [256][56][56]
    const float* __restrict__ p_gw,       // guard_w
    float* __restrict__ out)              // [B][256][56][56]
{
    __shared__ union {
        signed char bh[2][BH_SZ];                 // K-loop B images (cc=0,1)
        float       ep[128 * EP_STRIDE];          // epilogue transpose image
    } smem;
    __shared__ float c2s[2 * 56];

    int tid = threadIdx.x;
    int wv = tid >> 6, lane = tid & 63;
    int xl = lane & 15, q = lane >> 4;
    int p = blockIdx.x, cb = blockIdx.y;
    int b = p / 28, hp = p - b * 28;
    int h = hp * 2;                        // 2 output rows per block
    int wm0 = (wv >> 1) * 64;              // cout half within 128
    int row = wv & 1;                      // n half: output row 0/1

    // c2 box filter for this block's 2 output rows (s_pad L2-hot)
    if (tid < 112) {
        int rr = tid / 56, wp = tid - rr * 56;
        const float* sp = s_pad + ((size_t)(b * YP + h + rr)) * XP + wp;
        float a = 0.f;
        #pragma unroll
        for (int dy = 0; dy < 3; ++dy)
            #pragma unroll
            for (int dx = 0; dx < 3; ++dx)
                a += sp[dy * XP + dx];
        c2s[tid] = a;
    }

    const signed char* xb = xqU + (size_t)(b * YP + h) * XP * CIN_;

    // stage activation halo for cin-half cc_ into bh[cc_]; lane-permuted so
    // the LDS image carries the bank-swizzle (slot' = slot ^ ((x>>1)&3)).
    #define STAGE_B(cc_)                                                    \
        {                                                                   \
            signed char* dstb = smem.bh[cc_];                               \
            _Pragma("unroll")                                               \
            for (int r_ = 0; r_ < 4; ++r_) {                                \
                int T_ = r_ * 256 + tid;                                    \
                int p_ = T_ & 3;                                            \
                int x_ = (T_ >> 2) & 63;                                    \
                int yy_ = T_ >> 8;                                          \
                int q_ = p_ ^ ((x_ >> 1) & 3);                              \
                gload16(xb + (size_t)(yy_ * XP + x_) * CIN_ + (cc_) * 64 + q_ * 16, \
                        dstb + (r_ * 256 + wv * 64) * 16);                  \
            }                                                               \
        }

    // stage both cin-halves up-front (32 KB total, one vmcnt drain)
    STAGE_B(0)
    STAGE_B(1)

    int aoff = (wm0 + xl) * 64 + q * 16;   // bytes into a weight tile

    // prefetch A fragments for g=0 (both cc) while B staging is in flight
    i32x4 a0[2][4];
    #pragma unroll
    for (int cc = 0; cc < 2; ++cc)
        #pragma unroll
        for (int mi = 0; mi < 4; ++mi)
            a0[cc][mi] = *(const i32x4*)(
                wt + (size_t)((0 * 2 + cc) * 2 + cb) * 8192 + aoff + mi * 1024);

    i32x4 acc[4][4];
    #pragma unroll
    for (int mi = 0; mi < 4; ++mi)
        #pragma unroll
        for (int ni = 0; ni < 4; ++ni)
            acc[mi][ni] = (i32x4){0, 0, 0, 0};

    __syncthreads();      // B images + c2s ready (vmcnt+lgkm drained)

    #pragma unroll
    for (int g = 0; g < 9; ++g) {
        // issue next-g A loads first: independent, stay in flight across the
        // ds_reads + 32 MFMAs below (fine-grained vmcnt pipelining)
        i32x4 an[2][4];
        if (g < 8) {
            #pragma unroll
            for (int cc = 0; cc < 2; ++cc)
                #pragma unroll
                for (int mi = 0; mi < 4; ++mi)
                    an[cc][mi] = *(const i32x4*)(
                        wt + (size_t)(((g + 1) * 2 + cc) * 2 + cb) * 8192 +
                        aoff + mi * 1024);
        }
        int dy = g / 3, dx = g - dy * 3;
        int slot = q ^ (((xl + dx) >> 1) & 3);
        int boff = (row + dy) * 4096 + (xl + dx) * 64 + slot * 16;
        i32x4 bf[2][4];
        #pragma unroll
        for (int cc = 0; cc < 2; ++cc)
            #pragma unroll
            for (int ni = 0; ni < 4; ++ni)
                bf[cc][ni] = *(const i32x4*)(smem.bh[cc] + boff + ni * 1024);
        #pragma unroll
        for (int cc = 0; cc < 2; ++cc)
            #pragma unroll
            for (int mi = 0; mi < 4; ++mi)
                #pragma unroll
                for (int ni = 0; ni < 4; ++ni)
                    acc[mi][ni] = __builtin_amdgcn_mfma_i32_16x16x64_i8(
                        a0[cc][mi], bf[cc][ni], acc[mi][ni], 0, 0, 0);
        #pragma unroll
        for (int cc = 0; cc < 2; ++cc)
            #pragma unroll
            for (int mi = 0; mi < 4; ++mi)
                a0[cc][mi] = an[cc][mi];
    }

    __syncthreads();   // all LDS reads of bh done; smem is now ep

    // ---- epilogue: per output row, transpose acc through LDS, then
    //      w-contiguous float4 bias-load/FMA/store bursts ----
    float gw = p_gw[0];
    int cout_l = tid & 127;                    // this thread's cout (read phase)
    int half   = tid >> 7;                     // w half: 0 -> w<28, 1 -> w>=28
    int cout_g = cb * 128 + cout_l;
    float fs = fps[cout_g];
    float A  = gw * fs;                        // * ep (= 2*acc)
    float K0 = 256.0f * gw * Wsum[cout_g] * fs;
    float B0 = wzp[cout_g] * fs;

    #pragma unroll
    for (int r2 = 0; r2 < 2; ++r2) {
        // write phase: waves owning output-row r2 dump acc into ep image
        if (row == r2) {
            #pragma unroll
            for (int mi = 0; mi < 4; ++mi)
                #pragma unroll
                for (int ni = 0; ni < 4; ++ni)
                    #pragma unroll
                    for (int r = 0; r < 4; ++r)
                        smem.ep[(wm0 + mi * 16 + q * 4 + r) * EP_STRIDE +
                                ni * 16 + xl] = 2.0f * (float)acc[mi][ni][r];
        }
        __syncthreads();
        // read phase: all 256 threads; 7 float4 per thread along w
        {
            int hrow = h + r2;
            const float* brow = bias + ((size_t)cout_g * H_ + hrow) * W_;
            float* orow = out + (((size_t)b * COUT_ + cout_g) * H_ + hrow) * W_;
            const float* eprow = smem.ep + cout_l * EP_STRIDE;
            const float* c2row = c2s + r2 * 56;
            #pragma unroll
            for (int j = 0; j < 7; ++j) {
                int w4 = (half * 7 + j) * 4;   // 0..52, step 4
                f32x4 e = *(const f32x4*)(eprow + w4);
                f32x4 bi = *(const f32x4*)(brow + w4);
                f32x4 c2v = *(const f32x4*)(c2row + w4);
                f32x4 v;
                #pragma unroll
                for (int kq = 0; kq < 4; ++kq)
                    v[kq] = A * e[kq] + K0 + B0 * c2v[kq] + bi[kq];
                *(f32x4*)(orow + w4) = v;
            }
        }
        if (r2 == 0) __syncthreads();   // before row-1 waves overwrite ep
    }
}

// ---------------------------------------------------------------------------
extern "C" void kernel_launch(void* const* d_in, const int* in_sizes, int n_in,
                              void* d_out, int out_size, void* d_ws, size_t ws_size,
                              hipStream_t stream)
{
    const float* x     = (const float*)d_in[0];
    const float* wht   = (const float*)d_in[1];
    const float* act_s = (const float*)d_in[2];
    const float* act_q = (const float*)d_in[3];
    const float* azp   = (const float*)d_in[4];
    const float* wzp   = (const float*)d_in[5];
    const float* fps   = (const float*)d_in[6];
    const float* bias  = (const float*)d_in[7];
    const float* ga    = (const float*)d_in[8];
    const float* gw    = (const float*)d_in[9];
    float* out = (float*)d_out;

    char* ws = (char*)d_ws;
    // workspace (16B-aligned offsets):
    //   xqU  : 16*58*64*128 i8 = 7,602,176 B
    //   wt   : 294,912 B
    //   s_pad: 59,392 fp32     =   237,568 B
    //   Wsum : 256 fp32        =     1,024 B      (total ~8.1 MB)
    signed char* xqU  = (signed char*)(ws);
    signed char* wt   = (signed char*)(ws + 7602176);
    float*       spad = (float*)(ws + 7602176 + 294912);
    float*       Wsum = (float*)(ws + 7602176 + 294912 + 237568);

    k_prep<<<dim3(1232), dim3(256), 0, stream>>>(
        x, wht, act_s, act_q, azp, ga, xqU, wt, spad, Wsum);
    k_gemm<<<dim3(448, 2), dim3(256), 0, stream>>>(
        xqU, wt, spad, Wsum, wzp, fps, bias, gw, out);
}